// Round 1
// baseline (368.191 us; speedup 1.0000x reference)
//
#include <hip/hip_runtime.h>

// Factorized Gumbel-max sampler.
// Inputs (setup_inputs order):
//   d_in[0] q0     : float32 [8]            (2,2,2) root log-prob table
//   d_in[1] qg     : float32 [7*64]         (G-1, 2,2,2, 2,2,2) conditional tables
//   d_in[2] noise0 : float32 [N*8]          Gumbel noise for group 0
//   d_in[3] noise  : float32 [7*N*8]        Gumbel noise for groups 1..7
// Output: int32 [N*24] bits, out[i*24 + g*3 + b]

#define NGROUPS 8

__global__ __launch_bounds__(256) void fd_sample_kernel(
    const float* __restrict__ q0,
    const float* __restrict__ qg,
    const float* __restrict__ noise0,
    const float* __restrict__ noise,
    int* __restrict__ out,
    int N)
{
    const int i = blockIdx.x * blockDim.x + threadIdx.x;
    if (i >= N) return;

    // ---- Preload all Gumbel noise for this sample: 8 groups x 8 floats ----
    float nz[NGROUPS][8];
    {
        const float4* p = (const float4*)noise0 + (size_t)i * 2;
        float4 a = p[0], b = p[1];
        nz[0][0] = a.x; nz[0][1] = a.y; nz[0][2] = a.z; nz[0][3] = a.w;
        nz[0][4] = b.x; nz[0][5] = b.y; nz[0][6] = b.z; nz[0][7] = b.w;
    }
#pragma unroll
    for (int g = 1; g < NGROUPS; ++g) {
        const float4* p = (const float4*)noise + ((size_t)(g - 1) * N + i) * 2;
        float4 a = p[0], b = p[1];
        nz[g][0] = a.x; nz[g][1] = a.y; nz[g][2] = a.z; nz[g][3] = a.w;
        nz[g][4] = b.x; nz[g][5] = b.y; nz[g][6] = b.z; nz[g][7] = b.w;
    }

    int idxs[NGROUPS];

    // ---- Group 0: argmax over q0 + noise0 (q0 loads are wave-uniform -> s_load) ----
    {
        int   best_i = 0;
        float best_v = q0[0] + nz[0][0];
#pragma unroll
        for (int k = 1; k < 8; ++k) {
            float v = q0[k] + nz[0][k];
            if (v > best_v) { best_v = v; best_i = k; }  // strict > == first-max tie-break
        }
        idxs[0] = best_i;
    }

    // ---- Groups 1..7: gather conditional slice by previous idx, argmax ----
#pragma unroll
    for (int g = 1; g < NGROUPS; ++g) {
        const float4* tp = (const float4*)(qg + ((size_t)(g - 1) * 64 + (size_t)idxs[g - 1] * 8));
        float4 ta = tp[0], tb = tp[1];  // 32B-aligned, L1-resident (table is 1792B)
        float t[8] = { ta.x, ta.y, ta.z, ta.w, tb.x, tb.y, tb.z, tb.w };

        int   best_i = 0;
        float best_v = t[0] + nz[g][0];
#pragma unroll
        for (int k = 1; k < 8; ++k) {
            float v = t[k] + nz[g][k];
            if (v > best_v) { best_v = v; best_i = k; }
        }
        idxs[g] = best_i;
    }

    // ---- Emit 24 int32 bits as 6 aligned int4 stores (96B/thread, 16B-aligned) ----
    int bits[24];
#pragma unroll
    for (int g = 0; g < NGROUPS; ++g) {
        bits[g * 3 + 0] = (idxs[g] >> 2) & 1;
        bits[g * 3 + 1] = (idxs[g] >> 1) & 1;
        bits[g * 3 + 2] = idxs[g] & 1;
    }
    int4* op = (int4*)out + (size_t)i * 6;
#pragma unroll
    for (int j = 0; j < 6; ++j)
        op[j] = make_int4(bits[j * 4 + 0], bits[j * 4 + 1], bits[j * 4 + 2], bits[j * 4 + 3]);
}

extern "C" void kernel_launch(void* const* d_in, const int* in_sizes, int n_in,
                              void* d_out, int out_size, void* d_ws, size_t ws_size,
                              hipStream_t stream) {
    const float* q0     = (const float*)d_in[0];
    const float* qg     = (const float*)d_in[1];
    const float* noise0 = (const float*)d_in[2];
    const float* noise  = (const float*)d_in[3];
    int* out = (int*)d_out;

    const int N = in_sizes[2] / 8;  // noise0 is N*8 floats

    const int block = 256;
    const int grid  = (N + block - 1) / block;
    fd_sample_kernel<<<grid, block, 0, stream>>>(q0, qg, noise0, noise, out, N);
}

// Round 2
// 355.833 us; speedup vs baseline: 1.0347x; 1.0347x over previous
//
#include <hip/hip_runtime.h>

// Factorized Gumbel-max sampler — round 2.
// Inputs (setup_inputs order):
//   d_in[0] q0     : float32 [8]       root log-prob table (wave-uniform -> s_load)
//   d_in[1] qg     : float32 [7*64]    conditional tables (staged to LDS)
//   d_in[2] noise0 : float32 [N*8]     Gumbel noise, group 0
//   d_in[3] noise  : float32 [7*N*8]   Gumbel noise, groups 1..7
// Output: int32 [N*24] bits, out[i*24 + g*3 + b]
//
// Design: 1 thread/sample; double-buffered noise (16 live floats, low VGPR);
// table gathers from LDS (short chain, 2-way-max bank conflicts = free);
// output transposed through LDS (byte-packed, stride-7 dwords, conflict-free)
// so global stores are lane-contiguous int4 (fully coalesced).

#define NGROUPS 8

__global__ __launch_bounds__(256, 6) void fd_sample_kernel(
    const float* __restrict__ q0,
    const float* __restrict__ qg,
    const float* __restrict__ noise0,
    const float* __restrict__ noise,
    int* __restrict__ out,
    int N)
{
    __shared__ __align__(16) float s_tab[7 * 64];     // 1792 B
    __shared__ unsigned int s_out[256 * 7];           // 24 B/sample packed, stride 7 dwords

    const int t = threadIdx.x;

    // ---- Stage conditional tables into LDS (112 x float4 = 448 floats) ----
    if (t < 112)
        ((float4*)s_tab)[t] = ((const float4*)qg)[t];

    const int  i      = blockIdx.x * blockDim.x + t;
    const bool active = (i < N);
    const int  ii     = active ? i : (N - 1);         // clamp: keep loads in-bounds, no early return (barriers!)

    // ---- Group 0 noise + prefetch group 1 (double buffer: 16 live floats) ----
    const float4* p0 = (const float4*)noise0 + (size_t)ii * 2;
    float4 ca = p0[0], cb = p0[1];
    const float4* p1 = (const float4*)noise + (size_t)ii * 2;      // slab g=1 is noise[0]
    float4 pa = p1[0], pb = p1[1];

    int idxs[NGROUPS];

    // ---- Group 0: argmax over q0 + noise0 (q0 indices uniform -> scalar loads) ----
    {
        float n[8] = {ca.x, ca.y, ca.z, ca.w, cb.x, cb.y, cb.z, cb.w};
        float bv = q0[0] + n[0];
        int   bi = 0;
#pragma unroll
        for (int k = 1; k < 8; ++k) {
            float v = q0[k] + n[k];
            if (v > bv) { bv = v; bi = k; }           // strict > == first-max tie-break (matches jnp.argmax)
        }
        idxs[0] = bi;
    }

    __syncthreads();                                  // table staged

    // ---- Groups 1..7: LDS gather by previous idx, argmax; prefetch next noise ----
#pragma unroll
    for (int g = 1; g < NGROUPS; ++g) {
        ca = pa; cb = pb;
        if (g < NGROUPS - 1) {
            const float4* pn = (const float4*)noise + ((size_t)g * N + ii) * 2;  // slab for group g+1
            pa = pn[0]; pb = pn[1];
        }
        const float4* tp = (const float4*)(s_tab + (g - 1) * 64 + idxs[g - 1] * 8);  // 32B aligned
        float4 ta = tp[0], tb = tp[1];
        float tt[8] = {ta.x, ta.y, ta.z, ta.w, tb.x, tb.y, tb.z, tb.w};
        float nn[8] = {ca.x, ca.y, ca.z, ca.w, cb.x, cb.y, cb.z, cb.w};

        float bv = tt[0] + nn[0];
        int   bi = 0;
#pragma unroll
        for (int k = 1; k < 8; ++k) {
            float v = tt[k] + nn[k];
            if (v > bv) { bv = v; bi = k; }
        }
        idxs[g] = bi;
    }

    // ---- Pack 24 bit-values as bytes into 6 dwords; stage in LDS (stride 7: conflict-free) ----
    {
        unsigned int by[24];
#pragma unroll
        for (int g = 0; g < NGROUPS; ++g) {
            by[g * 3 + 0] = (idxs[g] >> 2) & 1;
            by[g * 3 + 1] = (idxs[g] >> 1) & 1;
            by[g * 3 + 2] = idxs[g] & 1;
        }
#pragma unroll
        for (int d = 0; d < 6; ++d)
            s_out[t * 7 + d] = by[4 * d] | (by[4 * d + 1] << 8) |
                               (by[4 * d + 2] << 16) | (by[4 * d + 3] << 24);
    }

    __syncthreads();

    // ---- Coalesced write-out: lane-contiguous int4 stores (1 KB/wave/instr) ----
    // Block's out region: 256 samples * 24 ints = 1536 int4s; int4 k = j*256 + t
    // covers out dwords 4k..4k+3 -> sample s = k/6, within-sample dword e = k%6,
    // which is exactly LDS dword s*7 + e (4 packed bytes).
    const size_t block_i4 = (size_t)blockIdx.x * 1536;
#pragma unroll
    for (int j = 0; j < 6; ++j) {
        int k = j * 256 + t;
        int s = k / 6;
        int e = k - s * 6;
        unsigned int w  = s_out[s * 7 + e];
        int gs = blockIdx.x * 256 + s;
        if (gs < N) {
            int4 o = make_int4((int)(w & 0xffu), (int)((w >> 8) & 0xffu),
                               (int)((w >> 16) & 0xffu), (int)(w >> 24));
            ((int4*)out)[block_i4 + k] = o;
        }
    }
}

extern "C" void kernel_launch(void* const* d_in, const int* in_sizes, int n_in,
                              void* d_out, int out_size, void* d_ws, size_t ws_size,
                              hipStream_t stream) {
    const float* q0     = (const float*)d_in[0];
    const float* qg     = (const float*)d_in[1];
    const float* noise0 = (const float*)d_in[2];
    const float* noise  = (const float*)d_in[3];
    int* out = (int*)d_out;

    const int N = in_sizes[2] / 8;  // noise0 is N*8 floats

    const int block = 256;
    const int grid  = (N + block - 1) / block;
    fd_sample_kernel<<<grid, block, 0, stream>>>(q0, qg, noise0, noise, out, N);
}

// Round 3
// 339.384 us; speedup vs baseline: 1.0849x; 1.0485x over previous
//
#include <hip/hip_runtime.h>

// Factorized Gumbel-max sampler — round 3.
//   d_in[0] q0     : float32 [8]       root table (wave-uniform -> s_load)
//   d_in[1] qg     : float32 [7*64]    conditional tables (staged to LDS)
//   d_in[2] noise0 : float32 [N*8]     Gumbel noise, group 0
//   d_in[3] noise  : float32 [7*N*8]   Gumbel noise, groups 1..7
// Output: int32 [N*24] bits.
//
// R3 design: ALL 16 noise float4 loads issued up-front (one pipelined latency
// window — R2's rolling prefetch exposed ~750 cyc per group), nontemporal
// loads/stores (streaming; don't thrash L2), LDS table gathers (short dep
// chain), LDS transpose for fully-coalesced int4 stores.

#define NGROUPS 8

typedef float  f4  __attribute__((ext_vector_type(4)));
typedef int    i4  __attribute__((ext_vector_type(4)));

__global__ __launch_bounds__(256, 4) void fd_sample_kernel(
    const float* __restrict__ q0,
    const float* __restrict__ qg,
    const float* __restrict__ noise0,
    const float* __restrict__ noise,
    int* __restrict__ out,
    int N)
{
    __shared__ __align__(16) float s_tab[7 * 64];     // 1792 B
    __shared__ unsigned int s_out[256 * 7];           // packed bits, stride 7 (conflict-free)

    const int t = threadIdx.x;

    // ---- Stage conditional tables into LDS ----
    if (t < 112)
        ((f4*)s_tab)[t] = ((const f4*)qg)[t];

    const int i  = blockIdx.x * blockDim.x + t;
    const int ii = (i < N) ? i : (N - 1);             // clamp (no early return: barriers)

    // ---- Issue ALL noise loads up-front: 16 independent nontemporal float4s ----
    f4 nv[16];
    {
        const f4* p = (const f4*)noise0 + (size_t)ii * 2;
        nv[0] = __builtin_nontemporal_load(p);
        nv[1] = __builtin_nontemporal_load(p + 1);
    }
#pragma unroll
    for (int g = 1; g < NGROUPS; ++g) {
        const f4* p = (const f4*)noise + ((size_t)(g - 1) * N + ii) * 2;
        nv[2 * g]     = __builtin_nontemporal_load(p);
        nv[2 * g + 1] = __builtin_nontemporal_load(p + 1);
    }

    int idxs[NGROUPS];

    // ---- Group 0: argmax over q0 + noise0 (strict > == first-max, matches jnp.argmax) ----
    {
        f4 a = nv[0], b = nv[1];
        float n[8] = {a.x, a.y, a.z, a.w, b.x, b.y, b.z, b.w};
        float bv = q0[0] + n[0];
        int   bi = 0;
#pragma unroll
        for (int k = 1; k < 8; ++k) {
            float v = q0[k] + n[k];
            if (v > bv) { bv = v; bi = k; }
        }
        idxs[0] = bi;
    }

    __syncthreads();                                  // table staged

    // ---- Groups 1..7: LDS gather by previous idx, argmax ----
#pragma unroll
    for (int g = 1; g < NGROUPS; ++g) {
        const f4* tp = (const f4*)(s_tab + (g - 1) * 64 + idxs[g - 1] * 8);  // 32B aligned
        f4 ta = tp[0], tb = tp[1];
        f4 na = nv[2 * g], nb = nv[2 * g + 1];
        float tt[8] = {ta.x, ta.y, ta.z, ta.w, tb.x, tb.y, tb.z, tb.w};
        float nn[8] = {na.x, na.y, na.z, na.w, nb.x, nb.y, nb.z, nb.w};

        float bv = tt[0] + nn[0];
        int   bi = 0;
#pragma unroll
        for (int k = 1; k < 8; ++k) {
            float v = tt[k] + nn[k];
            if (v > bv) { bv = v; bi = k; }
        }
        idxs[g] = bi;
    }

    // ---- Pack 24 bit-values as bytes into 6 dwords; stage in LDS ----
    {
        unsigned int by[24];
#pragma unroll
        for (int g = 0; g < NGROUPS; ++g) {
            by[g * 3 + 0] = (idxs[g] >> 2) & 1;
            by[g * 3 + 1] = (idxs[g] >> 1) & 1;
            by[g * 3 + 2] = idxs[g] & 1;
        }
#pragma unroll
        for (int d = 0; d < 6; ++d)
            s_out[t * 7 + d] = by[4 * d] | (by[4 * d + 1] << 8) |
                               (by[4 * d + 2] << 16) | (by[4 * d + 3] << 24);
    }

    __syncthreads();

    // ---- Coalesced nontemporal write-out: lane-contiguous int4 stores ----
    // int4 k = j*256 + t covers out dwords 4k..4k+3 -> sample s = k/6,
    // dword e = k%6 -> LDS dword s*7 + e (4 packed bytes).
    const size_t block_i4 = (size_t)blockIdx.x * 1536;
#pragma unroll
    for (int j = 0; j < 6; ++j) {
        int k = j * 256 + t;
        int s = k / 6;
        int e = k - s * 6;
        unsigned int w = s_out[s * 7 + e];
        int gs = blockIdx.x * 256 + s;
        if (gs < N) {
            i4 o = { (int)(w & 0xffu), (int)((w >> 8) & 0xffu),
                     (int)((w >> 16) & 0xffu), (int)(w >> 24) };
            __builtin_nontemporal_store(o, (i4*)out + block_i4 + k);
        }
    }
}

extern "C" void kernel_launch(void* const* d_in, const int* in_sizes, int n_in,
                              void* d_out, int out_size, void* d_ws, size_t ws_size,
                              hipStream_t stream) {
    const float* q0     = (const float*)d_in[0];
    const float* qg     = (const float*)d_in[1];
    const float* noise0 = (const float*)d_in[2];
    const float* noise  = (const float*)d_in[3];
    int* out = (int*)d_out;

    const int N = in_sizes[2] / 8;  // noise0 is N*8 floats

    const int block = 256;
    const int grid  = (N + block - 1) / block;
    fd_sample_kernel<<<grid, block, 0, stream>>>(q0, qg, noise0, noise, out, N);
}